// Round 1
// baseline (357.848 us; speedup 1.0000x reference)
//
#include <hip/hip_runtime.h>
#include <math.h>

#define DIM 4096

// Bank-conflict-free storage swizzle: slot(i) keeps bits 4-11, low4 = x^y^z.
// GF(2)-linear, so slot(a^b) = slot(a)^slot(b).
__device__ __forceinline__ int slot_of(int i) {
  return (i & 0xFF0) | ((i ^ (i >> 4) ^ (i >> 8)) & 15);
}

// Composite CNOT ladder (0,1)(1,2)...(10,11)(11,0) as amplitude-index source map:
// s_k = d_k^d_{k+1} (k<=9), s10 = d10^d11^d0, s11 = d11^d0.  GF(2)-linear.
__device__ __forceinline__ int cnot_src(int d) {
  return (d ^ (d >> 1)) ^ ((d & 1) * 0xC00);
}

// Apply SU(2) gate G = [[a, b], [-conj(b), conj(a)]], g = (ar, ai, br, bi)
__device__ __forceinline__ void gate2(float2& A, float2& B, const float4 g) {
  const float2 u = A, w = B;
  A.x = g.x * u.x - g.y * u.y + g.z * w.x - g.w * w.y;
  A.y = g.x * u.y + g.y * u.x + g.z * w.y + g.w * w.x;
  B.x = -g.z * u.x - g.w * u.y + g.x * w.x + g.y * w.y;
  B.y = -g.z * u.y + g.w * u.x + g.x * w.y - g.y * w.x;
}

// Apply 4 commuting 1q gates across the 4 local bits of v[16].
// gK acts on local bit K.
__device__ __forceinline__ void sweep4(float2 (&v)[16], const float4 g0, const float4 g1,
                                       const float4 g2, const float4 g3) {
#pragma unroll
  for (int p = 0; p < 16; p += 2) gate2(v[p], v[p + 1], g0);
#pragma unroll
  for (int p = 0; p < 16; ++p)
    if (!(p & 2)) gate2(v[p], v[p + 2], g1);
#pragma unroll
  for (int p = 0; p < 16; ++p)
    if (!(p & 4)) gate2(v[p], v[p + 4], g2);
#pragma unroll
  for (int p = 0; p < 8; ++p) gate2(v[p], v[p + 8], g3);
}

// Fuse RZ(lam)*RY(phi)*RX(th) into SU(2) (a, b); 48 gates = DEPTH*NQ.
__global__ void make_gates(const float* __restrict__ ax, const float* __restrict__ ay,
                           const float* __restrict__ az, float4* __restrict__ g) {
  int id = threadIdx.x;
  if (id < 48) {
    float th = 0.5f * ax[id], ph = 0.5f * ay[id], lm = 0.5f * az[id];
    float c = cosf(th), s = sinf(th);
    float cy = cosf(ph), sy = sinf(ph);
    float cl = cosf(lm), sl = sinf(lm);
    // M = Ry*Rx: m00 = cy*c + i*sy*s ; m01 = -sy*c - i*cy*s
    float m00r = cy * c, m00i = sy * s;
    float m01r = -sy * c, m01i = -cy * s;
    // a = e^{-i lm} * m00 ; b = e^{-i lm} * m01   (e^{-i lm} = cl - i sl)
    g[id] = make_float4(cl * m00r + sl * m00i, cl * m00i - sl * m00r,
                        cl * m01r + sl * m01i, cl * m01i - sl * m01r);
  }
}

// One block per batch element; state (4096 complex) lives in LDS (32 KB -> 5 blocks/CU cap).
__global__ __launch_bounds__(256, 4) void qsim(const float* __restrict__ x,
                                               const float4* __restrict__ gates,
                                               float* __restrict__ out) {
  __shared__ float2 st[DIM];
  const int t = threadIdx.x;
  const int b = blockIdx.x;
  const float* xb = x + (size_t)b * DIM;

  // ---- load |x|, block-reduce sum and sum-of-squares ----
  // Ownership i = t + 256*j matches the Z-pass, so layer-0 Z runs straight from regs.
  float w[16];
  float sw = 0.f, sw2 = 0.f;
#pragma unroll
  for (int j = 0; j < 16; ++j) {
    float a = fabsf(xb[t + (j << 8)]);
    w[j] = a;
    sw += a;
    sw2 += a * a;
  }
#pragma unroll
  for (int off = 32; off; off >>= 1) {
    sw += __shfl_down(sw, off, 64);
    sw2 += __shfl_down(sw2, off, 64);
  }
  if ((t & 63) == 0) st[t >> 6] = make_float2(sw, sw2);
  __syncthreads();
  {
    float2 p0 = st[0], p1 = st[1], p2 = st[2], p3 = st[3];
    sw = (p0.x + p1.x) + (p2.x + p3.x);
    sw2 = (p0.y + p1.y) + (p2.y + p3.y);
  }
  __syncthreads();

  // ---- amplitude encoding (faithful to reference branches) ----
  // s>1e-8: wn = w/sqrt(s); norm = sqrt(S2/s); state = wn/max(norm,1e-8)
  float2 v[16];
  if (sw > 1e-8f) {
    float wnscale = rsqrtf(fmaxf(sw, 1e-8f));
    float norm = sqrtf(sw2 / sw);
    float sc = (norm > 1e-8f) ? (wnscale / fmaxf(norm, 1e-8f)) : wnscale;
#pragma unroll
    for (int j = 0; j < 16; ++j) v[j] = make_float2(w[j] * sc, 0.f);
  } else {
#pragma unroll
    for (int j = 0; j < 16; ++j) v[j] = make_float2(0.015625f, 0.f);  // 1/64, norm=1
  }

  // Per-thread LDS address bases (everything else is a compile-time XOR const).
  const int AZr = slot_of(cnot_src(t));                       // Z-pass read (pi-folded)
  const int AZw = slot_of(t);                                 // Z-pass write
  const int AY = slot_of(((t >> 4) << 8) | (t & 15));         // Y-pass
  const int AX = slot_of(((t >> 4) << 8) | ((t & 15) << 4));  // X-pass

  for (int l = 0; l < 4; ++l) {
    const float4* gl = gates + l * 12;

    // ===== pass Z: qubits 0-3 (index bits 11-8); reads apply previous layer's CNOT ladder =====
    if (l) {
#pragma unroll
      for (int j = 0; j < 16; ++j) v[j] = st[AZr ^ slot_of(cnot_src(j << 8))];
      __syncthreads();  // all pi-reads done before anyone overwrites
    }
    sweep4(v, gl[3], gl[2], gl[1], gl[0]);  // local bit k -> qubit 3-k
#pragma unroll
    for (int j = 0; j < 16; ++j) st[AZw ^ slot_of(j << 8)] = v[j];
    __syncthreads();

    // ===== pass Y: qubits 4-7 (bits 7-4); exclusive in-place ownership, 1 barrier =====
#pragma unroll
    for (int j = 0; j < 16; ++j) v[j] = st[AY ^ slot_of(j << 4)];
    sweep4(v, gl[7], gl[6], gl[5], gl[4]);
#pragma unroll
    for (int j = 0; j < 16; ++j) st[AY ^ slot_of(j << 4)] = v[j];
    __syncthreads();

    // ===== pass X: qubits 8-11 (bits 3-0) =====
#pragma unroll
    for (int j = 0; j < 16; ++j) v[j] = st[AX ^ slot_of(j)];
    sweep4(v, gl[11], gl[10], gl[9], gl[8]);
#pragma unroll
    for (int j = 0; j < 16; ++j) st[AX ^ slot_of(j)] = v[j];
    __syncthreads();
  }

  // ---- output |amp|, with the final layer's CNOT ladder folded into the read ----
  float* ob = out + (size_t)b * DIM;
#pragma unroll
  for (int j = 0; j < 16; ++j) {
    float2 a = st[AZr ^ slot_of(cnot_src(j << 8))];
    ob[t + (j << 8)] = sqrtf(a.x * a.x + a.y * a.y);
  }
}

extern "C" void kernel_launch(void* const* d_in, const int* in_sizes, int n_in,
                              void* d_out, int out_size, void* d_ws, size_t ws_size,
                              hipStream_t stream) {
  const float* x = (const float*)d_in[0];
  const float* ax = (const float*)d_in[1];
  const float* ay = (const float*)d_in[2];
  const float* az = (const float*)d_in[3];
  float4* gates = (float4*)d_ws;  // 48 * 16 B = 768 B of workspace
  make_gates<<<1, 64, 0, stream>>>(ax, ay, az, gates);
  qsim<<<4096, 256, 0, stream>>>(x, gates, (float*)d_out);
}

// Round 2
// 320.177 us; speedup vs baseline: 1.1177x; 1.1177x over previous
//
#include <hip/hip_runtime.h>
#include <math.h>

#define DIM 4096

// Bank-conflict-free storage swizzle: slot(i) keeps bits 4-11, low4 = x^y^z.
// GF(2)-linear, so slot(a^b) = slot(a)^slot(b).
__device__ __forceinline__ int slot_of(int i) {
  return (i & 0xFF0) | ((i ^ (i >> 4) ^ (i >> 8)) & 15);
}

// Composite CNOT ladder (0,1)(1,2)...(10,11)(11,0) as amplitude-index source map:
// s_k = d_k^d_{k+1} (k<=9), s10 = d10^d11^d0, s11 = d11^d0.  GF(2)-linear.
__device__ __forceinline__ int cnot_src(int d) {
  return (d ^ (d >> 1)) ^ ((d & 1) * 0xC00);
}

// Apply SU(2) gate G = [[a, b], [-conj(b), conj(a)]], g = (ar, ai, br, bi)
__device__ __forceinline__ void gate2(float2& A, float2& B, const float4 g) {
  const float2 u = A, w = B;
  A.x = g.x * u.x - g.y * u.y + g.z * w.x - g.w * w.y;
  A.y = g.x * u.y + g.y * u.x + g.z * w.y + g.w * w.x;
  B.x = -g.z * u.x - g.w * u.y + g.x * w.x + g.y * w.y;
  B.y = -g.z * u.y + g.w * u.x + g.x * w.y - g.y * w.x;
}

// Apply 4 commuting 1q gates across the 4 local bits of v[16].
// gK acts on local bit K.
__device__ __forceinline__ void sweep4(float2 (&v)[16], const float4 g0, const float4 g1,
                                       const float4 g2, const float4 g3) {
#pragma unroll
  for (int p = 0; p < 16; p += 2) gate2(v[p], v[p + 1], g0);
#pragma unroll
  for (int p = 0; p < 16; ++p)
    if (!(p & 2)) gate2(v[p], v[p + 2], g1);
#pragma unroll
  for (int p = 0; p < 16; ++p)
    if (!(p & 4)) gate2(v[p], v[p + 4], g2);
#pragma unroll
  for (int p = 0; p < 8; ++p) gate2(v[p], v[p + 8], g3);
}

// Fuse RZ(lam)*RY(phi)*RX(th) into SU(2) (a, b); 48 gates = DEPTH*NQ.
__global__ void make_gates(const float* __restrict__ ax, const float* __restrict__ ay,
                           const float* __restrict__ az, float4* __restrict__ g) {
  int id = threadIdx.x;
  if (id < 48) {
    float th = 0.5f * ax[id], ph = 0.5f * ay[id], lm = 0.5f * az[id];
    float c = cosf(th), s = sinf(th);
    float cy = cosf(ph), sy = sinf(ph);
    float cl = cosf(lm), sl = sinf(lm);
    // M = Ry*Rx: m00 = cy*c + i*sy*s ; m01 = -sy*c - i*cy*s
    float m00r = cy * c, m00i = sy * s;
    float m01r = -sy * c, m01i = -cy * s;
    // a = e^{-i lm} * m00 ; b = e^{-i lm} * m01   (e^{-i lm} = cl - i sl)
    g[id] = make_float4(cl * m00r + sl * m00i, cl * m00i - sl * m00r,
                        cl * m01r + sl * m01i, cl * m01i - sl * m01r);
  }
}

// One block per batch element; state (4096 complex) lives in LDS (32 KB -> 5 blocks/CU cap).
// launch_bounds(256, 2): VGPR cap 256 — R1 showed (256,4) squeezed to 64 VGPRs and
// spilled ~30 floats/thread (FETCH 125MB/WRITE 192MB vs 64/67 ideal). Occupancy is
// LDS-bound at <=5 blocks/CU regardless, so the register cap was pure loss.
__global__ __launch_bounds__(256, 2) void qsim(const float* __restrict__ x,
                                               const float4* __restrict__ gates,
                                               float* __restrict__ out) {
  __shared__ float2 st[DIM];
  const int t = threadIdx.x;
  const int b = blockIdx.x;
  const float* xb = x + (size_t)b * DIM;

  // ---- load |x|, block-reduce sum and sum-of-squares ----
  // Ownership i = t + 256*j matches the Z-pass, so layer-0 Z runs straight from regs.
  float w[16];
  float sw = 0.f, sw2 = 0.f;
#pragma unroll
  for (int j = 0; j < 16; ++j) {
    float a = fabsf(xb[t + (j << 8)]);
    w[j] = a;
    sw += a;
    sw2 += a * a;
  }
#pragma unroll
  for (int off = 32; off; off >>= 1) {
    sw += __shfl_down(sw, off, 64);
    sw2 += __shfl_down(sw2, off, 64);
  }
  if ((t & 63) == 0) st[t >> 6] = make_float2(sw, sw2);
  __syncthreads();
  {
    float2 p0 = st[0], p1 = st[1], p2 = st[2], p3 = st[3];
    sw = (p0.x + p1.x) + (p2.x + p3.x);
    sw2 = (p0.y + p1.y) + (p2.y + p3.y);
  }
  __syncthreads();

  // ---- amplitude encoding (faithful to reference branches) ----
  // s>1e-8: wn = w/sqrt(s); norm = sqrt(S2/s); state = wn/max(norm,1e-8)
  float2 v[16];
  if (sw > 1e-8f) {
    float wnscale = rsqrtf(fmaxf(sw, 1e-8f));
    float norm = sqrtf(sw2 / sw);
    float sc = (norm > 1e-8f) ? (wnscale / fmaxf(norm, 1e-8f)) : wnscale;
#pragma unroll
    for (int j = 0; j < 16; ++j) v[j] = make_float2(w[j] * sc, 0.f);
  } else {
#pragma unroll
    for (int j = 0; j < 16; ++j) v[j] = make_float2(0.015625f, 0.f);  // 1/64, norm=1
  }

  // Per-thread LDS address bases (everything else is a compile-time XOR const).
  const int AZr = slot_of(cnot_src(t));                       // Z-pass read (pi-folded)
  const int AZw = slot_of(t);                                 // Z-pass write
  const int AY = slot_of(((t >> 4) << 8) | (t & 15));         // Y-pass
  const int AX = slot_of(((t >> 4) << 8) | ((t & 15) << 4));  // X-pass

#pragma unroll 1
  for (int l = 0; l < 4; ++l) {
    const float4* gl = gates + l * 12;

    // ===== pass Z: qubits 0-3 (index bits 11-8); reads apply previous layer's CNOT ladder =====
    if (l) {
#pragma unroll
      for (int j = 0; j < 16; ++j) v[j] = st[AZr ^ slot_of(cnot_src(j << 8))];
      __syncthreads();  // all pi-reads done before anyone overwrites
    }
    sweep4(v, gl[3], gl[2], gl[1], gl[0]);  // local bit k -> qubit 3-k
#pragma unroll
    for (int j = 0; j < 16; ++j) st[AZw ^ slot_of(j << 8)] = v[j];
    __syncthreads();

    // ===== pass Y: qubits 4-7 (bits 7-4); exclusive in-place ownership, 1 barrier =====
#pragma unroll
    for (int j = 0; j < 16; ++j) v[j] = st[AY ^ slot_of(j << 4)];
    sweep4(v, gl[7], gl[6], gl[5], gl[4]);
#pragma unroll
    for (int j = 0; j < 16; ++j) st[AY ^ slot_of(j << 4)] = v[j];
    __syncthreads();

    // ===== pass X: qubits 8-11 (bits 3-0) =====
#pragma unroll
    for (int j = 0; j < 16; ++j) v[j] = st[AX ^ slot_of(j)];
    sweep4(v, gl[11], gl[10], gl[9], gl[8]);
#pragma unroll
    for (int j = 0; j < 16; ++j) st[AX ^ slot_of(j)] = v[j];
    __syncthreads();
  }

  // ---- output |amp|, with the final layer's CNOT ladder folded into the read ----
  float* ob = out + (size_t)b * DIM;
#pragma unroll
  for (int j = 0; j < 16; ++j) {
    float2 a = st[AZr ^ slot_of(cnot_src(j << 8))];
    ob[t + (j << 8)] = sqrtf(a.x * a.x + a.y * a.y);
  }
}

extern "C" void kernel_launch(void* const* d_in, const int* in_sizes, int n_in,
                              void* d_out, int out_size, void* d_ws, size_t ws_size,
                              hipStream_t stream) {
  const float* x = (const float*)d_in[0];
  const float* ax = (const float*)d_in[1];
  const float* ay = (const float*)d_in[2];
  const float* az = (const float*)d_in[3];
  float4* gates = (float4*)d_ws;  // 48 * 16 B = 768 B of workspace
  make_gates<<<1, 64, 0, stream>>>(ax, ay, az, gates);
  qsim<<<4096, 256, 0, stream>>>(x, gates, (float*)d_out);
}

// Round 3
// 220.374 us; speedup vs baseline: 1.6238x; 1.4529x over previous
//
#include <hip/hip_runtime.h>
#include <math.h>

#define DIM 4096

typedef float f2 __attribute__((ext_vector_type(2)));

#if __has_builtin(__builtin_elementwise_fma)
#define PKFMA(a, b, c) __builtin_elementwise_fma((a), (b), (c))
#else
#define PKFMA(a, b, c) ((a) * (b) + (c))
#endif

// 6 packed constants per fused gate:
// c1=(ar,ar) c2=(-ai,ai) c3=(br,br) c4=(-bi,bi) c5=(-br,-br) c6=(ai,-ai)
struct GateP {
  f2 c1, c2, c3, c4, c5, c6;
};

// Bank-conflict-free storage swizzle: slot(i) keeps bits 4-11, low4 = x^y^z.
// GF(2)-linear, so slot(a^b) = slot(a)^slot(b).
__device__ __forceinline__ int slot_of(int i) {
  return (i & 0xFF0) | ((i ^ (i >> 4) ^ (i >> 8)) & 15);
}

// Composite CNOT ladder (0,1)(1,2)...(10,11)(11,0) as amplitude-index source map.
__device__ __forceinline__ int cnot_src(int d) {
  return (d ^ (d >> 1)) ^ ((d & 1) * 0xC00);
}

__device__ __forceinline__ f2 swap2(f2 v) { return __builtin_shufflevector(v, v, 1, 0); }

// SU(2) gate via packed fp32: A' = a*A + b*B ; B' = -conj(b)*A + conj(a)*B.
// 8 VOP3P ops (2 pk_mul + 6 pk_fma); swaps should fold into op_sel.
__device__ __forceinline__ void gate2(f2& A, f2& B, const GateP& g) {
  const f2 u = A, w = B;
  const f2 us = swap2(u), ws = swap2(w);
  f2 t = g.c1 * u;
  t = PKFMA(g.c2, us, t);
  t = PKFMA(g.c3, w, t);
  t = PKFMA(g.c4, ws, t);
  f2 r = g.c5 * u;
  r = PKFMA(g.c4, us, r);
  r = PKFMA(g.c1, w, r);
  r = PKFMA(g.c6, ws, r);
  A = t;
  B = r;
}

// Apply 4 commuting 1q gates across the 4 local bits of v[16]; gK acts on local bit K.
__device__ __forceinline__ void sweep4(f2 (&v)[16], const GateP& g0, const GateP& g1,
                                       const GateP& g2, const GateP& g3) {
#pragma unroll
  for (int p = 0; p < 16; p += 2) gate2(v[p], v[p + 1], g0);
#pragma unroll
  for (int p = 0; p < 16; ++p)
    if (!(p & 2)) gate2(v[p], v[p + 2], g1);
#pragma unroll
  for (int p = 0; p < 16; ++p)
    if (!(p & 4)) gate2(v[p], v[p + 4], g2);
#pragma unroll
  for (int p = 0; p < 8; ++p) gate2(v[p], v[p + 8], g3);
}

// Fuse RZ*RY*RX into SU(2) (a,b), expand into the 6 packed constants.
__global__ void make_gates(const float* __restrict__ ax, const float* __restrict__ ay,
                           const float* __restrict__ az, GateP* __restrict__ g) {
  int id = threadIdx.x;
  if (id < 48) {
    float th = 0.5f * ax[id], ph = 0.5f * ay[id], lm = 0.5f * az[id];
    float c = cosf(th), s = sinf(th);
    float cy = cosf(ph), sy = sinf(ph);
    float cl = cosf(lm), sl = sinf(lm);
    float m00r = cy * c, m00i = sy * s;
    float m01r = -sy * c, m01i = -cy * s;
    float ar = cl * m00r + sl * m00i, ai = cl * m00i - sl * m00r;
    float br = cl * m01r + sl * m01i, bi = cl * m01i - sl * m01r;
    GateP gp;
    gp.c1 = (f2){ar, ar};
    gp.c2 = (f2){-ai, ai};
    gp.c3 = (f2){br, br};
    gp.c4 = (f2){-bi, bi};
    gp.c5 = (f2){-br, -br};
    gp.c6 = (f2){ai, -ai};
    g[id] = gp;
  }
}

// One block per batch element; state (4096 complex) lives in LDS (32 KB).
// (256,2): R1 showed (256,4) forced 64 VGPRs and spilled; occupancy is LDS-bound anyway.
__global__ __launch_bounds__(256, 2) void qsim(const float* __restrict__ x,
                                               const GateP* __restrict__ gates,
                                               float* __restrict__ out) {
  __shared__ f2 st[DIM];
  const int t = threadIdx.x;
  const int b = blockIdx.x;
  const float* xb = x + (size_t)b * DIM;

  // ---- load |x|, block-reduce sum and sum-of-squares ----
  float w[16];
  float sw = 0.f, sw2 = 0.f;
#pragma unroll
  for (int j = 0; j < 16; ++j) {
    float a = fabsf(xb[t + (j << 8)]);
    w[j] = a;
    sw += a;
    sw2 += a * a;
  }
#pragma unroll
  for (int off = 32; off; off >>= 1) {
    sw += __shfl_down(sw, off, 64);
    sw2 += __shfl_down(sw2, off, 64);
  }
  if ((t & 63) == 0) st[t >> 6] = (f2){sw, sw2};
  __syncthreads();
  {
    f2 p0 = st[0], p1 = st[1], p2 = st[2], p3 = st[3];
    sw = (p0.x + p1.x) + (p2.x + p3.x);
    sw2 = (p0.y + p1.y) + (p2.y + p3.y);
  }
  __syncthreads();

  // ---- amplitude encoding (faithful to reference branches) ----
  f2 v[16];
  if (sw > 1e-8f) {
    float wnscale = rsqrtf(fmaxf(sw, 1e-8f));
    float norm = sqrtf(sw2 / sw);
    float sc = (norm > 1e-8f) ? (wnscale / fmaxf(norm, 1e-8f)) : wnscale;
#pragma unroll
    for (int j = 0; j < 16; ++j) v[j] = (f2){w[j] * sc, 0.f};
  } else {
#pragma unroll
    for (int j = 0; j < 16; ++j) v[j] = (f2){0.015625f, 0.f};  // 1/64, norm=1
  }

  // Per-thread LDS address bases (everything else is a compile-time XOR const).
  const int AZr = slot_of(cnot_src(t));                       // Z-pass read (pi-folded)
  const int AZw = slot_of(t);                                 // Z-pass write
  const int AY = slot_of(((t >> 4) << 8) | (t & 15));         // Y-pass
  const int AX = slot_of(((t >> 4) << 8) | ((t & 15) << 4));  // X-pass

#pragma unroll 1
  for (int l = 0; l < 4; ++l) {
    const GateP* gl = gates + l * 12;

    // ===== pass Z: qubits 0-3 (bits 11-8); reads apply previous layer's CNOT ladder =====
    if (l) {
#pragma unroll
      for (int j = 0; j < 16; ++j) v[j] = st[AZr ^ slot_of(cnot_src(j << 8))];
      __syncthreads();  // all pi-reads done before anyone overwrites
    }
    sweep4(v, gl[3], gl[2], gl[1], gl[0]);  // local bit k -> qubit 3-k
#pragma unroll
    for (int j = 0; j < 16; ++j) st[AZw ^ slot_of(j << 8)] = v[j];
    __syncthreads();

    // ===== pass Y: qubits 4-7 (bits 7-4); in-place ownership, 1 barrier =====
#pragma unroll
    for (int j = 0; j < 16; ++j) v[j] = st[AY ^ slot_of(j << 4)];
    sweep4(v, gl[7], gl[6], gl[5], gl[4]);
#pragma unroll
    for (int j = 0; j < 16; ++j) st[AY ^ slot_of(j << 4)] = v[j];
    __syncthreads();

    // ===== pass X: qubits 8-11 (bits 3-0) =====
#pragma unroll
    for (int j = 0; j < 16; ++j) v[j] = st[AX ^ slot_of(j)];
    sweep4(v, gl[11], gl[10], gl[9], gl[8]);
#pragma unroll
    for (int j = 0; j < 16; ++j) st[AX ^ slot_of(j)] = v[j];
    __syncthreads();
  }

  // ---- output |amp|, final layer's CNOT ladder folded into the read ----
  float* ob = out + (size_t)b * DIM;
#pragma unroll
  for (int j = 0; j < 16; ++j) {
    f2 a = st[AZr ^ slot_of(cnot_src(j << 8))];
    ob[t + (j << 8)] = sqrtf(a.x * a.x + a.y * a.y);
  }
}

extern "C" void kernel_launch(void* const* d_in, const int* in_sizes, int n_in,
                              void* d_out, int out_size, void* d_ws, size_t ws_size,
                              hipStream_t stream) {
  const float* x = (const float*)d_in[0];
  const float* ax = (const float*)d_in[1];
  const float* ay = (const float*)d_in[2];
  const float* az = (const float*)d_in[3];
  GateP* gates = (GateP*)d_ws;  // 48 * 48 B = 2304 B of workspace
  make_gates<<<1, 64, 0, stream>>>(ax, ay, az, gates);
  qsim<<<4096, 256, 0, stream>>>(x, gates, (float*)d_out);
}

// Round 4
// 209.473 us; speedup vs baseline: 1.7083x; 1.0520x over previous
//
#include <hip/hip_runtime.h>
#include <math.h>

#define DIM 4096

typedef _Float16 v8h __attribute__((ext_vector_type(8)));
typedef float v4f __attribute__((ext_vector_type(4)));

// Bank swizzle: low4 = a[3:0]^a[7:4]^a[11:8], bit4 = a4^a11^a7, high bits = a.
// XOR-linear, bijective. Hand-checked: every access pattern in this kernel
// (3 pass-reads, 3 pass-writes incl. pi-composed, encode, epilogue) maps a
// wave's 64 lanes onto banks with <=2-way aliasing (free per m136).
__device__ __forceinline__ int Lmap(int a) {
  return a ^ (((a >> 4) ^ (a >> 8)) & 15) ^ ((((a >> 11) ^ (a >> 7)) & 1) << 4);
}

// CNOT ladder as dest->src map: pi(d) = (d ^ (d>>1)) ^ ((d&1)*0xC00).
// Inverse = parity-corrected gray decode (verified: pinv(pi(d)) == d).
__device__ __forceinline__ int pinv(int s) {
  int p = __popc(s) & 1;
  int d = s ^ (p ? 0xC00 : 0);
  d ^= d >> 1; d ^= d >> 2; d ^= d >> 4; d ^= d >> 8;
  return d & 4095;
}

// ---- Pass: apply 16x16 complex matrix M (pass's 4 qubits) to state [16 x 256].
// State in LDS SoA planes: pl[0..4095] = re, pl[4096..8191] = im (fp32).
// Each wave owns 64 columns (4 tiles of 16) -> in-place, no cross-wave hazard,
// except PASS==2 which writes pi-permuted (CNOT fold) -> read-all/barrier/write.
template <int PASS>
__device__ __forceinline__ void do_pass(float* pl, const v8h* __restrict__ Af,
                                        int mat, int t) {
  constexpr int SHIFT = (2 - PASS) * 4;
  const int lane = t & 63, wv = t >> 6;
  const int m = lane & 15, q = lane >> 4, qb = q & 1, pm = q >> 1;
  // A-fragments (fp16, pre-packed in A[m=lane&15][k=quad*8+j] order):
  // re-comp: k<16 -> Mr, k>=16 -> -Mi ; im-comp: k<16 -> Mi, k>=16 -> Mr
  const v8h a_re = Af[(mat * 2 + 0) * 64 + lane];
  const v8h a_im = Af[(mat * 2 + 1) * 64 + lane];

  if constexpr (PASS < 2) {
#pragma unroll
    for (int tt = 0; tt < 4; ++tt) {
      const int col8 = wv * 64 + tt * 16 + m;
      int colamp;
      if constexpr (PASS == 0) colamp = col8;                       // cols = a[7:0]
      else colamp = ((col8 & 0xF0) << 4) | (col8 & 15);             // cols = a[11:8],a[3:0]
      // B-frag: lane supplies B[k=q*8+j][n=m]; k<16 -> Sr row k, k>=16 -> Si row k-16
      const int ramp = colamp | (qb << (SHIFT + 3));
      const int rb = (Lmap(ramp) << 2) | (pm << 14);
      float v[8];
#pragma unroll
      for (int j = 0; j < 8; ++j)
        v[j] = *(const float*)((const char*)pl + (rb ^ (Lmap(j << SHIFT) << 2)));
      v8h bh;
#pragma unroll
      for (int j = 0; j < 8; ++j) bh[j] = (_Float16)v[j];
      v4f cre = __builtin_amdgcn_mfma_f32_16x16x32_f16(a_re, bh, (v4f){0.f, 0.f, 0.f, 0.f}, 0, 0, 0);
      v4f cim = __builtin_amdgcn_mfma_f32_16x16x32_f16(a_im, bh, (v4f){0.f, 0.f, 0.f, 0.f}, 0, 0, 0);
      // C layout: col = lane&15, row = q*4 + r (verified m89/m91, dtype-independent)
      const int wb = Lmap(colamp | ((q * 4) << SHIFT)) << 2;
#pragma unroll
      for (int r = 0; r < 4; ++r) {
        const int ad = wb ^ (Lmap(r << SHIFT) << 2);
        *(float*)((char*)pl + ad) = cre[r];
        *(float*)((char*)pl + (ad | (1 << 14))) = cim[r];
      }
    }
    __syncthreads();
  } else {
    // PASS 2: rows = a[3:0]; writes apply this layer's CNOT ladder (pi-fold),
    // which scatters across other waves' columns -> two-phase with barrier.
    v8h bh[4];
#pragma unroll
    for (int tt = 0; tt < 4; ++tt) {
      const int col8 = wv * 64 + tt * 16 + m;
      const int colamp = ((col8 & 0xF0) << 4) | ((col8 & 15) << 4);  // a[11:8], a[7:4]
      const int rb = (Lmap(colamp | (qb << 3)) << 2) | (pm << 14);
      float v[8];
#pragma unroll
      for (int j = 0; j < 8; ++j)
        v[j] = *(const float*)((const char*)pl + (rb ^ (Lmap(j) << 2)));
#pragma unroll
      for (int j = 0; j < 8; ++j) bh[tt][j] = (_Float16)v[j];
    }
    __syncthreads();
#pragma unroll
    for (int tt = 0; tt < 4; ++tt) {
      const int col8 = wv * 64 + tt * 16 + m;
      const int colamp = ((col8 & 0xF0) << 4) | ((col8 & 15) << 4);
      v4f cre = __builtin_amdgcn_mfma_f32_16x16x32_f16(a_re, bh[tt], (v4f){0.f, 0.f, 0.f, 0.f}, 0, 0, 0);
      v4f cim = __builtin_amdgcn_mfma_f32_16x16x32_f16(a_im, bh[tt], (v4f){0.f, 0.f, 0.f, 0.f}, 0, 0, 0);
      const int wb = Lmap(pinv(colamp | (q * 4))) << 2;
#pragma unroll
      for (int r = 0; r < 4; ++r) {
        const int ad = wb ^ (Lmap(pinv(r)) << 2);
        *(float*)((char*)pl + ad) = cre[r];
        *(float*)((char*)pl + (ad | (1 << 14))) = cim[r];
      }
    }
    __syncthreads();
  }
}

// Fuse RZ*RY*RX per (layer,qubit), then build the 12 per-pass 16x16 complex
// kron matrices directly in MFMA A-fragment order, fp16, into d_ws.
__global__ void make_gates2(const float* __restrict__ ax, const float* __restrict__ ay,
                            const float* __restrict__ az, _Float16* __restrict__ Aw) {
  __shared__ float g4[48][4];  // ar, ai, br, bi per (layer,qubit)
  const int id = threadIdx.x;
  if (id < 48) {
    float th = 0.5f * ax[id], ph = 0.5f * ay[id], lm = 0.5f * az[id];
    float c = cosf(th), s = sinf(th);
    float cy = cosf(ph), sy = sinf(ph);
    float cl = cosf(lm), sl = sinf(lm);
    float m00r = cy * c, m00i = sy * s;
    float m01r = -sy * c, m01i = -cy * s;
    g4[id][0] = cl * m00r + sl * m00i;
    g4[id][1] = cl * m00i - sl * m00r;
    g4[id][2] = cl * m01r + sl * m01i;
    g4[id][3] = cl * m01i - sl * m01r;
  }
  __syncthreads();
  const int mat = id >> 6, lane = id & 63;
  const int m = lane & 15, q = lane >> 4;
  const int layer = mat / 3, pass = mat % 3, qbase = pass * 4;
#pragma unroll
  for (int j = 0; j < 8; ++j) {
    const int k = q * 8 + j, kk = k & 15;
    // M[m][kk] = prod over 4 qubits; i/k MSB (bit3) <-> qubit qbase (kron order:
    // qubit 0 most significant, matching the reference's state reshape).
    float cr = 1.f, ci = 0.f;
#pragma unroll
    for (int bp = 3; bp >= 0; --bp) {
      const int qq = qbase + (3 - bp);
      const int ib = (m >> bp) & 1, kb = (kk >> bp) & 1;
      const float* gg = g4[layer * 12 + qq];
      float er, ei;
      if (ib == 0 && kb == 0) { er = gg[0]; ei = gg[1]; }        // a
      else if (ib == 0 && kb == 1) { er = gg[2]; ei = gg[3]; }   // b
      else if (ib == 1 && kb == 0) { er = -gg[2]; ei = gg[3]; }  // -conj(b)
      else { er = gg[0]; ei = -gg[1]; }                          // conj(a)
      const float nr = cr * er - ci * ei, ni = cr * ei + ci * er;
      cr = nr; ci = ni;
    }
    const float reval = (k < 16) ? cr : -ci;  // [Mr | -Mi]
    const float imval = (k < 16) ? ci : cr;   // [Mi |  Mr]
    Aw[((mat * 2 + 0) * 64 + lane) * 8 + j] = (_Float16)reval;
    Aw[((mat * 2 + 1) * 64 + lane) * 8 + j] = (_Float16)imval;
  }
}

// One block per batch element; fp32 state in LDS SoA planes (32 KB -> 5 blocks/CU).
// State pre-scaled x64 so fp16 MFMA inputs sit in ~N(0,1) range (rel err 2^-11/pass).
__global__ __launch_bounds__(256, 2) void qsim2(const float* __restrict__ x,
                                                const v8h* __restrict__ Af,
                                                float* __restrict__ out) {
  __shared__ float pl[2 * DIM];
  const int t = threadIdx.x;
  const int b = blockIdx.x;
  const float* xb = x + (size_t)b * DIM;

  // ---- load |x|, block-reduce sum & sum-of-squares ----
  float w[16];
  float sw = 0.f, sw2 = 0.f;
#pragma unroll
  for (int j = 0; j < 16; ++j) {
    float a = fabsf(xb[t + (j << 8)]);
    w[j] = a; sw += a; sw2 += a * a;
  }
#pragma unroll
  for (int off = 32; off; off >>= 1) {
    sw += __shfl_down(sw, off, 64);
    sw2 += __shfl_down(sw2, off, 64);
  }
  if ((t & 63) == 0) { pl[t >> 6] = sw; pl[4 + (t >> 6)] = sw2; }
  __syncthreads();
  sw = (pl[0] + pl[1]) + (pl[2] + pl[3]);
  sw2 = (pl[4] + pl[5]) + (pl[6] + pl[7]);
  __syncthreads();

  // ---- amplitude encoding (faithful branches), x64 prescale ----
  float sc = 0.f;
  const bool ok = (sw > 1e-8f);
  if (ok) {
    float wnscale = rsqrtf(fmaxf(sw, 1e-8f));
    float norm = sqrtf(sw2 / sw);
    sc = ((norm > 1e-8f) ? (wnscale / fmaxf(norm, 1e-8f)) : wnscale) * 64.0f;
  }
#pragma unroll
  for (int j = 0; j < 16; ++j) {
    const int L = Lmap((j << 8) | t);
    pl[L] = ok ? w[j] * sc : 1.0f;  // else-branch: 1/64 * 64
    pl[DIM + L] = 0.0f;
  }
  __syncthreads();

#pragma unroll 1
  for (int l = 0; l < 4; ++l) {
    do_pass<0>(pl, Af, l * 3 + 0, t);  // qubits 0-3  (bits 11-8)
    do_pass<1>(pl, Af, l * 3 + 1, t);  // qubits 4-7  (bits 7-4)
    do_pass<2>(pl, Af, l * 3 + 2, t);  // qubits 8-11 (bits 3-0) + CNOT-ladder fold
  }

  // ---- output |amp| / 64 ----
  float* ob = out + (size_t)b * DIM;
#pragma unroll
  for (int j = 0; j < 16; ++j) {
    const int amp = (j << 8) | t;
    const int L = Lmap(amp);
    const float re = pl[L], im = pl[DIM + L];
    ob[amp] = sqrtf(re * re + im * im) * 0.015625f;
  }
}

extern "C" void kernel_launch(void* const* d_in, const int* in_sizes, int n_in,
                              void* d_out, int out_size, void* d_ws, size_t ws_size,
                              hipStream_t stream) {
  const float* x = (const float*)d_in[0];
  const float* ax = (const float*)d_in[1];
  const float* ay = (const float*)d_in[2];
  const float* az = (const float*)d_in[3];
  _Float16* Aw = (_Float16*)d_ws;  // 12 mats * 2 comps * 64 lanes * 8 halves = 24576 B
  make_gates2<<<1, 768, 0, stream>>>(ax, ay, az, Aw);
  qsim2<<<4096, 256, 0, stream>>>(x, (const v8h*)Aw, (float*)d_out);
}